// Round 5
// baseline (195.519 us; speedup 1.0000x reference)
//
#include <hip/hip_runtime.h>

// RecursiveNN root = sum of leaf embeddings: out[b,d] = sum_l emb[ids[b,l], d]
// B=4096, L=64, D=300, VOCAB=100000, fp32.
//
// R4: MLP-maximized. 2 waves/tree (32 rows each), 2048 blocks x 4 waves
// (32 waves/CU). Main loop: batches of 8 rows loaded into a static float4
// v[8] (8 x 1024B loads in flight), then accumulated. Tail (cols 256..299,
// 176B/row) packed 4 rows per wave-load: lane = 16*r + c, c<11 active
// (704B/load, 8 loads instead of 32), reduced with shfl_xor(16,32).

#define NB 4096
#define NL 64
#define ND 300
#define ND4 75   // float4 per row
#define NT 11    // tail float4 per row (cols 256..299)

__global__ __launch_bounds__(256, 8) void recnn_root_sum(
    const int* __restrict__ word_ids,     // [NB, NL]
    const float4* __restrict__ emb4,      // [VOCAB, ND4]
    float* __restrict__ out)              // [NB, ND]
{
    __shared__ float partial[4][ND];

    const int tid  = threadIdx.x;
    const int wave = tid >> 6;
    const int lane = tid & 63;

    const int tree_local = wave >> 1;          // 0..1
    const int half       = wave & 1;           // which 32 rows
    const int tree       = blockIdx.x * 2 + tree_local;

    // lanes 0..31 hold this wave's 32 leaf ids (32..63 duplicate).
    const int myid = word_ids[tree * NL + half * 32 + (lane & 31)];

    // ---- main: cols 0..255 of 32 rows, batches of 8 rows ----
    float4 acc0 = make_float4(0.f, 0.f, 0.f, 0.f);
    #pragma unroll 1
    for (int b = 0; b < 4; ++b) {
        float4 v[8];
        #pragma unroll
        for (int j = 0; j < 8; ++j) {
            const int row = __builtin_amdgcn_readlane(myid, b * 8 + j);
            v[j] = emb4[(size_t)row * ND4 + lane];
        }
        #pragma unroll
        for (int j = 0; j < 8; ++j) {
            acc0.x += v[j].x; acc0.y += v[j].y;
            acc0.z += v[j].z; acc0.w += v[j].w;
        }
    }

    // ---- tail: cols 256..299, packed 4 rows per wave-load ----
    const int rsel = lane >> 4;   // row-group 0..3
    const int csel = lane & 15;   // tail chunk, active if < NT
    float4 acct = make_float4(0.f, 0.f, 0.f, 0.f);
    {
        float4 t[8];
        #pragma unroll
        for (int j = 0; j < 8; ++j) {
            const int rj = __shfl(myid, 4 * j + rsel, 64);   // row ids[4j+rsel]
            if (csel < NT)
                t[j] = emb4[(size_t)rj * ND4 + 64 + csel];
        }
        if (csel < NT) {
            #pragma unroll
            for (int j = 0; j < 8; ++j) {
                acct.x += t[j].x; acct.y += t[j].y;
                acct.z += t[j].z; acct.w += t[j].w;
            }
        }
    }
    // reduce tail across the 4 row-groups (lanes differ in bits 4..5)
    acct.x += __shfl_xor(acct.x, 16, 64);
    acct.y += __shfl_xor(acct.y, 16, 64);
    acct.z += __shfl_xor(acct.z, 16, 64);
    acct.w += __shfl_xor(acct.w, 16, 64);
    acct.x += __shfl_xor(acct.x, 32, 64);
    acct.y += __shfl_xor(acct.y, 32, 64);
    acct.z += __shfl_xor(acct.z, 32, 64);
    acct.w += __shfl_xor(acct.w, 32, 64);

    // ---- per-wave partials to LDS ----
    *reinterpret_cast<float4*>(&partial[wave][lane * 4]) = acc0;
    if (rsel == 0 && csel < NT)
        *reinterpret_cast<float4*>(&partial[wave][256 + csel * 4]) = acct;
    __syncthreads();

    // ---- cross-wave reduce: tree t = partial[2t] + partial[2t+1] ----
    for (int t = tid; t < 2 * ND; t += 256) {
        const int tl = t / ND;
        const int c  = t - tl * ND;
        out[(size_t)(blockIdx.x * 2 + tl) * ND + c] =
            partial[2 * tl][c] + partial[2 * tl + 1][c];
    }
}

extern "C" void kernel_launch(void* const* d_in, const int* in_sizes, int n_in,
                              void* d_out, int out_size, void* d_ws, size_t ws_size,
                              hipStream_t stream) {
    const int*    word_ids = (const int*)d_in[0];      // [4096, 64] int32
    const float4* emb4     = (const float4*)d_in[1];   // [100000, 75] float4
    float*        out      = (float*)d_out;            // [4096, 300] f32

    recnn_root_sum<<<NB / 2, 256, 0, stream>>>(word_ids, emb4, out);
}